// Round 10
// baseline (35.576 us; speedup 1.0000x reference)
//
#include <hip/hip_runtime.h>

// YOLO layer: B=16, A=3, C=80, H=W=76, stride=8, scale_xy=1
// anchors/stride: a0=(1.5,2.0) a1=(2.375,4.5) a2=(5.0,3.5)
// R9 structure + 2 consecutive tiles per block (1104 blocks, fully co-resident)
// + bijective XCD swizzle (1104 = 8*138).

#define HW_    5776      // 76*76
#define W_     76
#define C_     80
#define A_     3
#define B_     16
#define N_     (A_ * HW_) // 17328
#define TILE_  128
#define TPP_   46        // tiles per plane; 45 full + tail of 16
#define PAIRS_ 23        // tile pairs per plane (46/2)
#define RC_    81        // dword row stride of packed conf LDS (odd -> spread banks)
#define NWG_   (B_ * A_ * PAIRS_)  // 1104 = 8 * 138
#define CPX_   (NWG_ / 8)          // 138 blocks per XCD

typedef float f32x4_ __attribute__((ext_vector_type(4)));

__device__ __forceinline__ float sigmoidf_(float x) {
    return __builtin_amdgcn_rcpf(1.0f + __expf(-x));
}

// pack two f32 as bf16 (truncate) into one dword: lo -> [15:0], hi -> [31:16]
__device__ __forceinline__ unsigned int pack2_(float lo, float hi) {
    return (__float_as_uint(hi) & 0xFFFF0000u) | (__float_as_uint(lo) >> 16);
}

__device__ __forceinline__ void store_nt4_(float* p, float x, float y, float z, float w) {
    f32x4_ v = {x, y, z, w};
    __builtin_nontemporal_store(v, (f32x4_*)p);
}

__global__ __launch_bounds__(320) void yolo_kernel(const float* __restrict__ in,
                                                   float* __restrict__ out) {
    // conf channels, bf16-packed: row r holds locations (2r, 2r+1), col = channel
    __shared__ unsigned int ldsP[TILE_ / 2][RC_];   // 64 x 81 dwords = 20.7 KB
    __shared__ float lds_det[TILE_];

    const int t = threadIdx.x;
    // XCD-aware bijective swizzle: HW round-robins blockIdx.x%8 across XCDs;
    // remap so each XCD owns a CONTIGUOUS run of 138 logical blocks.
    const int bid = (blockIdx.x & 7) * CPX_ + (blockIdx.x >> 3);

    const int plane = bid / PAIRS_;      // b*3 + a
    const int tp    = bid - plane * PAIRS_;
    const int a     = plane % A_;
    const int b     = plane / A_;
    const float* gp = in + (size_t)plane * 85 * HW_;

    const float invW = 1.0f / 76.0f;
    const float aw = (a == 0) ? 1.5f : (a == 1 ? 2.375f : 5.0f);
    const float ah = (a == 0) ? 2.0f : (a == 1 ? 4.5f : 3.5f);

    #pragma unroll
    for (int j = 0; j < 2; ++j) {
        const int tile       = tp * 2 + j;
        const int tile_start = tile * TILE_;
        const int nloc       = min(TILE_, HW_ - tile_start);
        const float* g       = gp + tile_start;

        if (t < 256) {
            // ---- conf loaders: 80 ch x 32 quads = 2560 float4, exactly 10/thread
            if (nloc == TILE_) {
                #pragma unroll
                for (int i = 0; i < 10; ++i) {
                    const int f  = t + 256 * i;
                    const int cc = f >> 5;           // conf channel 0..79
                    const int k  = (f & 31) << 2;    // location of .x
                    const float4 v =
                        *reinterpret_cast<const float4*>(g + (size_t)(5 + cc) * HW_ + k);
                    const int r = (f & 31) << 1;     // k/2
                    ldsP[r][cc]     = pack2_(v.x, v.y);
                    ldsP[r + 1][cc] = pack2_(v.z, v.w);
                }
            } else {
                #pragma unroll
                for (int i = 0; i < 10; ++i) {
                    const int f  = t + 256 * i;
                    const int cc = f >> 5;
                    const int k  = (f & 31) << 2;
                    if (k < nloc) {                  // nloc is a multiple of 4
                        const float4 v =
                            *reinterpret_cast<const float4*>(g + (size_t)(5 + cc) * HW_ + k);
                        const int r = (f & 31) << 1;
                        ldsP[r][cc]     = pack2_(v.x, v.y);
                        ldsP[r + 1][cc] = pack2_(v.z, v.w);
                    }
                }
            }
        } else {
            // ---- box wave (64 lanes): channels 0..4 straight from global
            #pragma unroll
            for (int jj = 0; jj < 2; ++jj) {
                const int l = (t - 256) + 64 * jj;
                if (l < nloc) {
                    const float x0 = g[0 * HW_ + l];
                    const float x1 = g[1 * HW_ + l];
                    const float x2 = g[2 * HW_ + l];
                    const float x3 = g[3 * HW_ + l];
                    const float x4 = g[4 * HW_ + l];

                    const int gs = tile_start + l;
                    const int h  = gs / W_;
                    const int w  = gs - h * W_;

                    const float bx = (sigmoidf_(x0) + (float)w) * invW;
                    const float by = (sigmoidf_(x1) + (float)h) * invW;
                    const float bw = __expf(x2) * (aw * invW);
                    const float bh = __expf(x3) * (ah * invW);
                    const float bx1 = bx - 0.5f * bw;
                    const float by1 = by - 0.5f * bh;

                    float* bo = out + ((size_t)b * N_ + a * HW_ + gs) * 4;
                    store_nt4_(bo, bx1, by1, bx1 + bw, by1 + bh);

                    lds_det[l] = sigmoidf_(x4);
                }
            }
        }
        __syncthreads();

        // ---- confs: nloc*20 float4 quads (full tile: 2560 = exactly 8/thread)
        float* co = out + (size_t)B_ * N_ * 4
                        + ((size_t)b * N_ + a * HW_ + tile_start) * C_;
        if (nloc == TILE_) {
            #pragma unroll
            for (int i = 0; i < 8; ++i) {
                const int q  = t + 320 * i;
                const int sl = q / 20;               // location in tile
                const int qc = (q - sl * 20) << 2;   // first of 4 channels
                const float det = lds_det[sl];
                const int r = sl >> 1;
                const unsigned int sh = (sl & 1) ? 0u : 16u;  // even loc = lo half
                const unsigned int w0 = ldsP[r][qc + 0];
                const unsigned int w1 = ldsP[r][qc + 1];
                const unsigned int w2 = ldsP[r][qc + 2];
                const unsigned int w3 = ldsP[r][qc + 3];
                store_nt4_(co + q * 4,
                           sigmoidf_(__uint_as_float((w0 << sh) & 0xFFFF0000u)) * det,
                           sigmoidf_(__uint_as_float((w1 << sh) & 0xFFFF0000u)) * det,
                           sigmoidf_(__uint_as_float((w2 << sh) & 0xFFFF0000u)) * det,
                           sigmoidf_(__uint_as_float((w3 << sh) & 0xFFFF0000u)) * det);
            }
        } else {
            const int total4 = nloc * 20;
            for (int q = t; q < total4; q += 320) {
                const int sl = q / 20;
                const int qc = (q - sl * 20) << 2;
                const float det = lds_det[sl];
                const int r = sl >> 1;
                const unsigned int sh = (sl & 1) ? 0u : 16u;
                const unsigned int w0 = ldsP[r][qc + 0];
                const unsigned int w1 = ldsP[r][qc + 1];
                const unsigned int w2 = ldsP[r][qc + 2];
                const unsigned int w3 = ldsP[r][qc + 3];
                store_nt4_(co + q * 4,
                           sigmoidf_(__uint_as_float((w0 << sh) & 0xFFFF0000u)) * det,
                           sigmoidf_(__uint_as_float((w1 << sh) & 0xFFFF0000u)) * det,
                           sigmoidf_(__uint_as_float((w2 << sh) & 0xFFFF0000u)) * det,
                           sigmoidf_(__uint_as_float((w3 << sh) & 0xFFFF0000u)) * det);
            }
        }
        if (j == 0) __syncthreads();   // LDS reused by next tile
    }
}

extern "C" void kernel_launch(void* const* d_in, const int* in_sizes, int n_in,
                              void* d_out, int out_size, void* d_ws, size_t ws_size,
                              hipStream_t stream) {
    const float* in = (const float*)d_in[0];
    float* out = (float*)d_out;
    yolo_kernel<<<NWG_, 320, 0, stream>>>(in, out);   // 1104 blocks, all co-resident
}

// Round 11
// 32.201 us; speedup vs baseline: 1.1048x; 1.1048x over previous
//
#include <hip/hip_runtime.h>

// YOLO layer: B=16, A=3, C=80, H=W=76, stride=8, scale_xy=1
// anchors/stride: a0=(1.5,2.0) a1=(2.375,4.5) a2=(5.0,3.5)
// R9 (best measured: 32.2us): TILE=128, 320 thr, bf16-packed LDS transpose,
// NT stores, bijective XCD swizzle (2208 = 8*276).

#define HW_   5776       // 76*76
#define W_    76
#define C_    80
#define A_    3
#define B_    16
#define N_    (A_ * HW_) // 17328
#define TILE_ 128
#define TPP_  46         // ceil(5776/128); 45 full tiles + tail of 16
#define RC_   81         // dword row stride of packed conf LDS (odd -> spread banks)
#define NWG_  (B_ * A_ * TPP_)   // 2208 = 8 * 276
#define CPX_  (NWG_ / 8)         // 276 blocks per XCD

typedef float f32x4_ __attribute__((ext_vector_type(4)));

__device__ __forceinline__ float sigmoidf_(float x) {
    return __builtin_amdgcn_rcpf(1.0f + __expf(-x));
}

// pack two f32 as bf16 (truncate) into one dword: lo -> [15:0], hi -> [31:16]
__device__ __forceinline__ unsigned int pack2_(float lo, float hi) {
    return (__float_as_uint(hi) & 0xFFFF0000u) | (__float_as_uint(lo) >> 16);
}

__device__ __forceinline__ void store_nt4_(float* p, float x, float y, float z, float w) {
    f32x4_ v = {x, y, z, w};
    __builtin_nontemporal_store(v, (f32x4_*)p);
}

__global__ __launch_bounds__(320) void yolo_kernel(const float* __restrict__ in,
                                                   float* __restrict__ out) {
    // conf channels, bf16-packed: row r holds locations (2r, 2r+1), col = channel
    __shared__ unsigned int ldsP[TILE_ / 2][RC_];   // 64 x 81 dwords = 20.7 KB
    __shared__ float lds_det[TILE_];

    const int t = threadIdx.x;
    // XCD-aware bijective swizzle: HW round-robins blockIdx.x%8 across XCDs;
    // remap so each XCD owns a CONTIGUOUS run of 276 logical blocks.
    const int bid = (blockIdx.x & 7) * CPX_ + (blockIdx.x >> 3);

    const int tile  = bid % TPP_;
    const int plane = bid / TPP_;        // b*3 + a
    const int a     = plane % A_;
    const int b     = plane / A_;
    const int tile_start = tile * TILE_;
    const int nloc  = min(TILE_, HW_ - tile_start);
    const float* g  = in + (size_t)plane * 85 * HW_ + tile_start;

    if (t < 256) {
        // ---- conf loaders: 80 ch x 32 quads = 2560 float4, exactly 10/thread
        if (nloc == TILE_) {
            #pragma unroll
            for (int i = 0; i < 10; ++i) {
                const int f  = t + 256 * i;
                const int cc = f >> 5;           // conf channel 0..79
                const int k  = (f & 31) << 2;    // location of .x
                const float4 v =
                    *reinterpret_cast<const float4*>(g + (size_t)(5 + cc) * HW_ + k);
                const int r = (f & 31) << 1;     // k/2
                ldsP[r][cc]     = pack2_(v.x, v.y);
                ldsP[r + 1][cc] = pack2_(v.z, v.w);
            }
        } else {
            #pragma unroll
            for (int i = 0; i < 10; ++i) {
                const int f  = t + 256 * i;
                const int cc = f >> 5;
                const int k  = (f & 31) << 2;
                if (k < nloc) {                  // nloc is a multiple of 4
                    const float4 v =
                        *reinterpret_cast<const float4*>(g + (size_t)(5 + cc) * HW_ + k);
                    const int r = (f & 31) << 1;
                    ldsP[r][cc]     = pack2_(v.x, v.y);
                    ldsP[r + 1][cc] = pack2_(v.z, v.w);
                }
            }
        }
    } else {
        // ---- box wave (64 lanes): channels 0..4 straight from global, 2 locs/lane
        #pragma unroll
        for (int j = 0; j < 2; ++j) {
            const int l = (t - 256) + 64 * j;
            if (l < nloc) {
                const float x0 = g[0 * HW_ + l];
                const float x1 = g[1 * HW_ + l];
                const float x2 = g[2 * HW_ + l];
                const float x3 = g[3 * HW_ + l];
                const float x4 = g[4 * HW_ + l];

                const int gs = tile_start + l;
                const int h  = gs / W_;
                const int w  = gs - h * W_;
                const float invW = 1.0f / 76.0f;
                const float aw = (a == 0) ? 1.5f : (a == 1 ? 2.375f : 5.0f);
                const float ah = (a == 0) ? 2.0f : (a == 1 ? 4.5f : 3.5f);

                const float bx = (sigmoidf_(x0) + (float)w) * invW;
                const float by = (sigmoidf_(x1) + (float)h) * invW;
                const float bw = __expf(x2) * (aw * invW);
                const float bh = __expf(x3) * (ah * invW);
                const float bx1 = bx - 0.5f * bw;
                const float by1 = by - 0.5f * bh;

                float* bo = out + ((size_t)b * N_ + a * HW_ + gs) * 4;
                store_nt4_(bo, bx1, by1, bx1 + bw, by1 + bh);

                lds_det[l] = sigmoidf_(x4);
            }
        }
    }
    __syncthreads();

    // ---- confs: nloc*20 float4 quads (full tile: 2560 = exactly 8/thread)
    float* co = out + (size_t)B_ * N_ * 4
                    + ((size_t)b * N_ + a * HW_ + tile_start) * C_;
    if (nloc == TILE_) {
        #pragma unroll
        for (int i = 0; i < 8; ++i) {
            const int q  = t + 320 * i;
            const int sl = q / 20;               // location in tile
            const int qc = (q - sl * 20) << 2;   // first of 4 channels
            const float det = lds_det[sl];
            const int r = sl >> 1;
            const unsigned int sh = (sl & 1) ? 0u : 16u;  // even loc = lo half
            const unsigned int w0 = ldsP[r][qc + 0];
            const unsigned int w1 = ldsP[r][qc + 1];
            const unsigned int w2 = ldsP[r][qc + 2];
            const unsigned int w3 = ldsP[r][qc + 3];
            store_nt4_(co + q * 4,
                       sigmoidf_(__uint_as_float((w0 << sh) & 0xFFFF0000u)) * det,
                       sigmoidf_(__uint_as_float((w1 << sh) & 0xFFFF0000u)) * det,
                       sigmoidf_(__uint_as_float((w2 << sh) & 0xFFFF0000u)) * det,
                       sigmoidf_(__uint_as_float((w3 << sh) & 0xFFFF0000u)) * det);
        }
    } else {
        const int total4 = nloc * 20;
        for (int q = t; q < total4; q += 320) {
            const int sl = q / 20;
            const int qc = (q - sl * 20) << 2;
            const float det = lds_det[sl];
            const int r = sl >> 1;
            const unsigned int sh = (sl & 1) ? 0u : 16u;
            const unsigned int w0 = ldsP[r][qc + 0];
            const unsigned int w1 = ldsP[r][qc + 1];
            const unsigned int w2 = ldsP[r][qc + 2];
            const unsigned int w3 = ldsP[r][qc + 3];
            store_nt4_(co + q * 4,
                       sigmoidf_(__uint_as_float((w0 << sh) & 0xFFFF0000u)) * det,
                       sigmoidf_(__uint_as_float((w1 << sh) & 0xFFFF0000u)) * det,
                       sigmoidf_(__uint_as_float((w2 << sh) & 0xFFFF0000u)) * det,
                       sigmoidf_(__uint_as_float((w3 << sh) & 0xFFFF0000u)) * det);
        }
    }
}

extern "C" void kernel_launch(void* const* d_in, const int* in_sizes, int n_in,
                              void* d_out, int out_size, void* d_ws, size_t ws_size,
                              hipStream_t stream) {
    const float* in = (const float*)d_in[0];
    float* out = (float*)d_out;
    yolo_kernel<<<NWG_, 320, 0, stream>>>(in, out);   // 2208 blocks
}